// Round 2
// baseline (311.237 us; speedup 1.0000x reference)
//
#include <hip/hip_runtime.h>
#include <hip/hip_bf16.h>

typedef __bf16 bf16x8 __attribute__((ext_vector_type(8)));
typedef float f32x4 __attribute__((ext_vector_type(4)));
typedef unsigned short u16x8 __attribute__((ext_vector_type(8)));
typedef unsigned short u16x2 __attribute__((ext_vector_type(2)));

#define B_    16
#define CIN   128
#define H_    112
#define W_    112
#define COUT  256
#define HO    54
#define WO    54
#define EH    56
#define EW    56
#define M_PER_B (HO*WO)      // 2916
#define PPOS  136            // LDS shorts per spatial position: 68 dwords -> (pos+ch)&7 bank spread
#define EBSTR 130            // prep LDS transpose row stride (65 dwords == 1 mod 32, conflict-free)

__device__ __forceinline__ unsigned short f2bf(float v) {
    __hip_bfloat16 h = __float2bfloat16(v);
    return __builtin_bit_cast(unsigned short, h);
}

// ---------------------------------------------------------------------------
// prep: block = (b,h). 448 threads = 16 c-groups x 28 w-slots (float4 each).
// Coalesced f4 loads; per-thread channel partial sums -> LDS reduce -> S.
// Even h: bf16 even-w subsample transposed in LDS -> channel-last E row.
// Tail blocks: W repack to Wb[tap][o][c] bf16.
// ---------------------------------------------------------------------------
__global__ __launch_bounds__(448) void prep_kernel(
    const float* __restrict__ in, const float* __restrict__ w,
    unsigned short* __restrict__ E, float* __restrict__ S,
    unsigned short* __restrict__ Wb)
{
    const int blk = blockIdx.x;
    const int tid = threadIdx.x;
    if (blk < B_ * H_) {
        __shared__ unsigned short Ebuf[EW * EBSTR];   // 14,560 B
        __shared__ f32x4 Spart[16][28];               //  7,168 B
        const int b = blk / H_, h = blk % H_;
        const int cg = tid / 28, ws = tid % 28;       // cg<16, ws<28
        const bool evenh = (h & 1) == 0;
        const float* rowb = in + ((size_t)(b * CIN) * H_ + h) * W_;
        f32x4 acc = (f32x4){0.f, 0.f, 0.f, 0.f};
        #pragma unroll
        for (int k = 0; k < 8; ++k) {
            int c = cg + k * 16;
            f32x4 v = *reinterpret_cast<const f32x4*>(rowb + (size_t)c * (H_ * W_) + ws * 4);
            acc += v;
            if (evenh) {
                Ebuf[(2 * ws)     * EBSTR + c] = f2bf(v[0]);   // w=4ws   -> j=2ws
                Ebuf[(2 * ws + 1) * EBSTR + c] = f2bf(v[2]);   // w=4ws+2 -> j=2ws+1
            }
        }
        Spart[cg][ws] = acc;
        __syncthreads();
        if (tid < 28) {
            f32x4 s = Spart[0][tid];
            #pragma unroll
            for (int g = 1; g < 16; ++g) s += Spart[g][tid];
            *reinterpret_cast<f32x4*>(S + (size_t)(b * H_ + h) * W_ + tid * 4) = s;
        }
        if (evenh) {
            unsigned short* Erow = E + (size_t)(b * EH + (h >> 1)) * EW * CIN;
            // 56*128 shorts = 3584 u16x2 chunks; 8 per thread, coalesced
            for (int f = tid; f < EW * CIN / 2; f += 448) {
                int j = f >> 6, cs = f & 63;
                *reinterpret_cast<u16x2*>(Erow + j * CIN + cs * 2) =
                    *reinterpret_cast<const u16x2*>(Ebuf + j * EBSTR + cs * 2);
            }
        }
    } else {
        // W repack: Wb[(t*COUT + o)*CIN + c] = bf16(w[(o*CIN + c)*9 + t])
        const int gt = (blk - B_ * H_) * 448 + tid;
        for (int idx = gt; idx < 9 * COUT * CIN; idx += 64 * 448) {
            int t   = idx / (COUT * CIN);
            int rem = idx % (COUT * CIN);             // o*CIN + c
            Wb[idx] = f2bf(w[(size_t)rem * 9 + t]);
        }
    }
}

// ---------------------------------------------------------------------------
// T[b,y,x] = 0.1 * (sum of 5x5 S patch - sum of even-even 3x3 subgrid)
// ---------------------------------------------------------------------------
__global__ __launch_bounds__(256) void t_kernel(
    const float* __restrict__ S, float* __restrict__ T)
{
    int idx = blockIdx.x * 256 + threadIdx.x;
    if (idx >= B_ * M_PER_B) return;
    int b = idx / M_PER_B, m = idx % M_PER_B;
    int y = m / WO, x = m % WO;
    const float* Sp = S + ((size_t)(b * H_) + 2 * y) * W_ + 2 * x;
    float s25 = 0.f, s9 = 0.f;
    #pragma unroll
    for (int i = 0; i < 5; ++i) {
        #pragma unroll
        for (int j = 0; j < 5; ++j) {
            float v = Sp[i * W_ + j];
            s25 += v;
            if (!(i & 1) && !(j & 1)) s9 += v;
        }
    }
    T[idx] = 0.1f * (s25 - s9);
}

// ---------------------------------------------------------------------------
// conv: block = (b, 1 output row). M=54 (4 x 16 subtiles, padded), N=256.
// LDS: 3 E-rows (45.7 KB) -> 3 blocks/CU. 8 waves = 2 m-groups x 4 n-groups,
// wave tile 32m x 64n (acc[2][4]). K-loop: 9 taps x 4 c-chunks, no barriers,
// B-frags from L2-resident Wb.
// ---------------------------------------------------------------------------
__global__ __launch_bounds__(512) void conv_kernel(
    const unsigned short* __restrict__ E, const unsigned short* __restrict__ Wb,
    const float* __restrict__ T, const float* __restrict__ bias1,
    float* __restrict__ out)
{
    __shared__ unsigned short patch[3 * EW * PPOS];   // 45,696 B

    const int tid = threadIdx.x;
    const int b = blockIdx.y;
    const int y = blockIdx.x;

    // stage E rows y..y+2 (contiguous 43,008 B span): 2688 chunks of 16B
    const unsigned short* Eg = E + (size_t)(b * EH + y) * EW * CIN;
    #pragma unroll
    for (int it = 0; it < 6; ++it) {
        int ch = tid + it * 512;
        if (it < 5 || ch < 2688) {
            int pos = ch >> 4, cs = ch & 15;
            *reinterpret_cast<u16x8*>(&patch[pos * PPOS + cs * 8]) =
                *reinterpret_cast<const u16x8*>(Eg + (size_t)ch * 8);
        }
    }
    __syncthreads();

    const int lane = tid & 63;
    const int wid  = tid >> 6;        // 0..7
    const int wm   = wid >> 2;        // 0..1
    const int wn   = wid & 3;         // 0..3
    const int lm   = lane & 15;
    const int kq   = lane >> 4;

    int aoff[2];
    #pragma unroll
    for (int mi = 0; mi < 2; ++mi) {
        int m = (wm * 2 + mi) * 16 + lm;
        if (m > 53) m = 53;                       // pad lanes duplicate x=53
        aoff[mi] = m * PPOS + kq * 8;             // x-position within patch row 0
    }
    int bcol[4];
    #pragma unroll
    for (int ni = 0; ni < 4; ++ni)
        bcol[ni] = (wn * 64 + ni * 16 + lm) * CIN + kq * 8;

    f32x4 acc[2][4];
    #pragma unroll
    for (int mi = 0; mi < 2; ++mi)
        #pragma unroll
        for (int ni = 0; ni < 4; ++ni)
            acc[mi][ni] = (f32x4){0.f, 0.f, 0.f, 0.f};

    #pragma unroll
    for (int t = 0; t < 9; ++t) {
        const int tapoff = ((t / 3) * EW + (t % 3)) * PPOS;
        const unsigned short* wt = Wb + (size_t)t * (COUT * CIN);
        #pragma unroll
        for (int c0 = 0; c0 < 128; c0 += 32) {
            bf16x8 a[2], bb[4];
            #pragma unroll
            for (int mi = 0; mi < 2; ++mi)
                a[mi] = __builtin_bit_cast(bf16x8,
                    *reinterpret_cast<const u16x8*>(&patch[aoff[mi] + tapoff + c0]));
            #pragma unroll
            for (int ni = 0; ni < 4; ++ni)
                bb[ni] = __builtin_bit_cast(bf16x8,
                    *reinterpret_cast<const u16x8*>(wt + bcol[ni] + c0));
            #pragma unroll
            for (int mi = 0; mi < 2; ++mi)
                #pragma unroll
                for (int ni = 0; ni < 4; ++ni)
                    acc[mi][ni] = __builtin_amdgcn_mfma_f32_16x16x32_bf16(
                        a[mi], bb[ni], acc[mi][ni], 0, 0, 0);
        }
    }

    // epilogue: out[b][o][y*54 + x] = acc + bias1[o] * T[b][y*54 + x]
    // row base y*54 may be only 8B-aligned -> float2 stores; x=52 is partial.
    const float* Trow = T + (size_t)b * M_PER_B + y * WO;
    float* obase = out + (size_t)b * COUT * M_PER_B + y * WO;
    #pragma unroll
    for (int mi = 0; mi < 2; ++mi) {
        int mb = (wm * 2 + mi) * 16 + kq * 4;     // x base of this f32x4
        if (mb >= WO) continue;                    // padded tail
        bool full = (mb + 4 <= WO);                // mb<=50 -> all 4 valid
        float tv0 = Trow[mb], tv1 = Trow[mb + 1];
        float tv2 = 0.f, tv3 = 0.f;
        if (full) { tv2 = Trow[mb + 2]; tv3 = Trow[mb + 3]; }
        #pragma unroll
        for (int ni = 0; ni < 4; ++ni) {
            int o = wn * 64 + ni * 16 + lm;
            float bo = bias1[o];
            float* op = obase + (size_t)o * M_PER_B + mb;
            float2 r01 = make_float2(acc[mi][ni][0] + bo * tv0,
                                     acc[mi][ni][1] + bo * tv1);
            *reinterpret_cast<float2*>(op) = r01;
            if (full) {
                float2 r23 = make_float2(acc[mi][ni][2] + bo * tv2,
                                         acc[mi][ni][3] + bo * tv3);
                *reinterpret_cast<float2*>(op + 2) = r23;
            }
        }
    }
}

// ---------------------------------------------------------------------------
extern "C" void kernel_launch(void* const* d_in, const int* in_sizes, int n_in,
                              void* d_out, int out_size, void* d_ws, size_t ws_size,
                              hipStream_t stream)
{
    const float* in = (const float*)d_in[0];
    const float* w  = (const float*)d_in[1];
    const float* b1 = (const float*)d_in[2];
    float* out = (float*)d_out;

    char* ws = (char*)d_ws;
    unsigned short* E  = (unsigned short*)ws;                  // 12,845,056 B
    size_t off = 12845056;
    float* S = (float*)(ws + off);  off += 802816;             // 16*112*112*4
    float* T = (float*)(ws + off);  off += 186624;             // 16*2916*4
    unsigned short* Wb = (unsigned short*)(ws + off);          // 589,824 B

    prep_kernel<<<dim3(B_ * H_ + 64), 448, 0, stream>>>(in, w, E, S, Wb);
    t_kernel<<<dim3((B_ * M_PER_B + 255) / 256), 256, 0, stream>>>(S, T);
    conv_kernel<<<dim3(HO, B_), 512, 0, stream>>>(E, Wb, T, b1, out);
}

// Round 3
// 229.737 us; speedup vs baseline: 1.3548x; 1.3548x over previous
//
#include <hip/hip_runtime.h>
#include <hip/hip_bf16.h>

typedef __bf16 bf16x8 __attribute__((ext_vector_type(8)));
typedef float f32x4 __attribute__((ext_vector_type(4)));
typedef unsigned short u16x8 __attribute__((ext_vector_type(8)));

#define B_    16
#define CIN   128
#define H_    112
#define W_    112
#define COUT  256
#define HO    54
#define WO    54
#define M_PER_B (HO*WO)        // 2916
#define HW    (H_*W_)          // 12544
#define SPLANE (B_*HW)         // 200704  (one c-quarter partial-sum plane)

__device__ __forceinline__ unsigned short f2bf(float v) {
    __hip_bfloat16 h = __float2bfloat16(v);
    return __builtin_bit_cast(unsigned short, h);
}

// ---------------------------------------------------------------------------
// K1: blocks 0..783: channel-sum partials Spart[q][b][h][w], q = c/32.
//     blocks 784..927: weight repack into fragment-ordered Wf:
//     Wf[((t*4+c0)*16+g)*512 + L*8 + e] = bf16(w[o][c][t]) with
//     o = g*16+(L&15), c = c0*32+(L>>4)*8+e  -> per-wave B-frag load is one
//     coalesced 1KB global_load_dwordx4.
// ---------------------------------------------------------------------------
__global__ __launch_bounds__(256) void sum_kernel(
    const float* __restrict__ in, const float* __restrict__ w,
    float* __restrict__ Spart, unsigned short* __restrict__ Wf)
{
    const int blk = blockIdx.x;
    const int tid = threadIdx.x;
    if (blk < 784) {
        int f  = blk * 256 + tid;          // ((q*16+b)*112+h)*28 + ws
        int ws = f % 28;
        int r  = f / 28;
        int h  = r % H_;
        int bq = r / H_;
        int b  = bq & 15;
        int q  = bq >> 4;
        const float* p = in + ((size_t)(b * CIN + q * 32) * H_ + h) * W_ + 4 * ws;
        f32x4 acc = (f32x4){0.f, 0.f, 0.f, 0.f};
        #pragma unroll
        for (int cc = 0; cc < 32; ++cc)
            acc += *reinterpret_cast<const f32x4*>(p + (size_t)cc * HW);
        *reinterpret_cast<f32x4*>(Spart + (size_t)bq * HW + h * W_ + 4 * ws) = acc;
    } else {
        int cid = (blk - 784) * 256 + tid;     // 0..36863 = ((t*4+c0)*16+g)*64+L
        int L   = cid & 63;
        int g   = (cid >> 6) & 15;
        int c0  = (cid >> 10) & 3;
        int t   = cid >> 12;                   // 0..8
        int o   = g * 16 + (L & 15);
        int cb  = c0 * 32 + (L >> 4) * 8;
        u16x8 v;
        #pragma unroll
        for (int e = 0; e < 8; ++e)
            v[e] = f2bf(w[(size_t)(o * CIN + cb + e) * 9 + t]);
        *reinterpret_cast<u16x8*>(Wf + (size_t)cid * 8) = v;
    }
}

// ---------------------------------------------------------------------------
// K2: T[b,y,x] = 0.1 * (sum 5x5 window - even-even 3x3 subgrid) of S,
//     S summed from the 4 partials inline.
// ---------------------------------------------------------------------------
__global__ __launch_bounds__(256) void t_kernel(
    const float* __restrict__ Spart, float* __restrict__ T)
{
    int idx = blockIdx.x * 256 + threadIdx.x;
    if (idx >= B_ * M_PER_B) return;
    int b = idx / M_PER_B, m = idx % M_PER_B;
    int y = m / WO, x = m % WO;
    float s25 = 0.f, s9 = 0.f;
    #pragma unroll
    for (int i = 0; i < 5; ++i) {
        #pragma unroll
        for (int j = 0; j < 5; ++j) {
            size_t off = (size_t)b * HW + (2 * y + i) * W_ + 2 * x + j;
            float v = Spart[off] + Spart[SPLANE + off] +
                      Spart[2 * SPLANE + off] + Spart[3 * SPLANE + off];
            s25 += v;
            if (!(i & 1) && !(j & 1)) s9 += v;
        }
    }
    T[idx] = 0.1f * (s25 - s9);
}

// ---------------------------------------------------------------------------
// K3: conv. Block = (b, y): stages 3 even input rows (fp32, L3-resident)
// as bf16 channel-last into XOR-swizzled LDS (43KB, conflict-free b128
// reads), then 36 K-steps (9 taps x 4 c-chunks) with 2-deep B prefetch.
// 4 waves, each 64m x 64n (acc[4][4]): 16 MFMA per 4 B-loads.
// ---------------------------------------------------------------------------
__global__ __launch_bounds__(256, 3) void conv_kernel(
    const float* __restrict__ in, const unsigned short* __restrict__ Wf,
    const float* __restrict__ T, const float* __restrict__ bias1,
    float* __restrict__ out)
{
    __shared__ unsigned short patch[168 * 128];      // 43,008 B

    const int tid = threadIdx.x;
    int bid = blockIdx.x;
    int wg  = (bid & 7) * 108 + (bid >> 3);          // XCD-contiguous (864%8==0)
    const int b = wg / HO;
    const int y = wg % HO;

    // stage: rows h = 2y, 2y+2, 2y+4; all 128 c, all 112 w; keep even w as bf16
    const float* inb = in + (size_t)b * CIN * HW;
    #pragma unroll
    for (int it = 0; it < 42; ++it) {
        int ch = tid + it * 256;          // ((c*3+r)*28+ws)
        int ws = ch % 28;
        int cr = ch / 28;
        int r  = cr % 3;
        int c  = cr / 3;
        f32x4 v = *reinterpret_cast<const f32x4*>(
            inb + ((size_t)c * H_ + (2 * y + 2 * r)) * W_ + 4 * ws);
        int p0 = r * 56 + 2 * ws;
        patch[p0 * 128 + (c ^ ((p0 & 7) << 3))] = f2bf(v[0]);
        int p1 = p0 + 1;
        patch[p1 * 128 + (c ^ ((p1 & 7) << 3))] = f2bf(v[2]);
    }
    __syncthreads();

    const int lane = tid & 63;
    const int wn   = tid >> 6;        // 0..3: n-group of 64 cols
    const int lm   = lane & 15;
    const int kq   = lane >> 4;
    const int koff = kq * 8;

    int xm[4];
    #pragma unroll
    for (int mi = 0; mi < 4; ++mi) {
        int x = mi * 16 + lm;
        xm[mi] = (x > 53) ? 53 : x;
    }

    f32x4 acc[4][4];
    #pragma unroll
    for (int mi = 0; mi < 4; ++mi)
        #pragma unroll
        for (int ni = 0; ni < 4; ++ni)
            acc[mi][ni] = (f32x4){0.f, 0.f, 0.f, 0.f};

    const unsigned short* wfl = Wf + (size_t)(wn * 4) * 512 + lane * 8;

    bf16x8 bb[2][4];
    #pragma unroll
    for (int ni = 0; ni < 4; ++ni)
        bb[0][ni] = __builtin_bit_cast(bf16x8,
            *reinterpret_cast<const u16x8*>(wfl + ni * 512));

    #pragma unroll
    for (int s = 0; s < 36; ++s) {
        const int cur = s & 1;
        if (s + 1 < 36) {
            const unsigned short* wnx = wfl + (size_t)(s + 1) * 16 * 512;
            #pragma unroll
            for (int ni = 0; ni < 4; ++ni)
                bb[cur ^ 1][ni] = __builtin_bit_cast(bf16x8,
                    *reinterpret_cast<const u16x8*>(wnx + ni * 512));
        }
        const int t  = s >> 2, c0 = s & 3;
        const int ki = t / 3, kj = t % 3;
        bf16x8 a[4];
        #pragma unroll
        for (int mi = 0; mi < 4; ++mi) {
            int pos = ki * 56 + kj + xm[mi];
            int sa  = pos * 128 + ((c0 * 32 + koff) ^ ((pos & 7) << 3));
            a[mi] = __builtin_bit_cast(bf16x8,
                *reinterpret_cast<const u16x8*>(&patch[sa]));
        }
        #pragma unroll
        for (int mi = 0; mi < 4; ++mi)
            #pragma unroll
            for (int ni = 0; ni < 4; ++ni)
                acc[mi][ni] = __builtin_amdgcn_mfma_f32_16x16x32_bf16(
                    a[mi], bb[cur][ni], acc[mi][ni], 0, 0, 0);
    }

    // epilogue: out[b][o][y*54+x] = acc + bias1[o]*T[b][y*54+x]
    const float* Trow = T + (size_t)b * M_PER_B + y * WO;
    float* obase = out + (size_t)b * COUT * M_PER_B + y * WO;
    #pragma unroll
    for (int mi = 0; mi < 4; ++mi) {
        int mb = mi * 16 + kq * 4;
        if (mb >= WO) continue;
        bool full = (mb + 4 <= WO);
        float tv0 = Trow[mb], tv1 = Trow[mb + 1];
        float tv2 = 0.f, tv3 = 0.f;
        if (full) { tv2 = Trow[mb + 2]; tv3 = Trow[mb + 3]; }
        #pragma unroll
        for (int ni = 0; ni < 4; ++ni) {
            int o = wn * 64 + ni * 16 + lm;
            float bo = bias1[o];
            float* op = obase + (size_t)o * M_PER_B + mb;
            float2 r01 = make_float2(acc[mi][ni][0] + bo * tv0,
                                     acc[mi][ni][1] + bo * tv1);
            *reinterpret_cast<float2*>(op) = r01;
            if (full) {
                float2 r23 = make_float2(acc[mi][ni][2] + bo * tv2,
                                         acc[mi][ni][3] + bo * tv3);
                *reinterpret_cast<float2*>(op + 2) = r23;
            }
        }
    }
}

// ---------------------------------------------------------------------------
extern "C" void kernel_launch(void* const* d_in, const int* in_sizes, int n_in,
                              void* d_out, int out_size, void* d_ws, size_t ws_size,
                              hipStream_t stream)
{
    const float* in = (const float*)d_in[0];
    const float* w  = (const float*)d_in[1];
    const float* b1 = (const float*)d_in[2];
    float* out = (float*)d_out;

    char* ws = (char*)d_ws;
    float* Spart = (float*)ws;                                 // 4*16*112*112*4 = 12,845,056
    size_t off = 12845056;
    float* T = (float*)(ws + off);  off += 186624;             // 16*2916*4
    unsigned short* Wf = (unsigned short*)(ws + off);          // 589,824

    sum_kernel<<<dim3(784 + 144), 256, 0, stream>>>(in, w, Spart, Wf);
    t_kernel<<<dim3((B_ * M_PER_B + 255) / 256), 256, 0, stream>>>(Spart, T);
    conv_kernel<<<dim3(HO * B_), 256, 0, stream>>>(in, Wf, T, b1, out);
}

// Round 5
// 229.421 us; speedup vs baseline: 1.3566x; 1.0014x over previous
//
#include <hip/hip_runtime.h>
#include <hip/hip_bf16.h>

typedef __bf16 bf16x8 __attribute__((ext_vector_type(8)));
typedef float f32x4 __attribute__((ext_vector_type(4)));
typedef unsigned short u16x8 __attribute__((ext_vector_type(8)));

#define B_    16
#define CIN   128
#define H_    112
#define W_    112
#define COUT  256
#define HO    54
#define WO    54
#define M_PER_B (HO*WO)        // 2916
#define HW    (H_*W_)          // 12544

__device__ __forceinline__ unsigned short f2bf(float v) {
    __hip_bfloat16 h = __float2bfloat16(v);
    return __builtin_bit_cast(unsigned short, h);
}

// ---------------------------------------------------------------------------
// K1: blocks 0..1791: S[b][h][w] = full 128-channel sum. Block=(b,h),
//     224 active threads = 8 cgroups x 28 w-slots, 16 f32x4 loads each,
//     LDS 8-way reduce. Tail blocks: weight repack into fragment-ordered Wf:
//     Wf[((t*4+c0)*16+g)*512 + L*8 + e] = bf16(w[o][c][t]),
//     o = g*16+(L&15), c = c0*32+(L>>4)*8+e.
// ---------------------------------------------------------------------------
__global__ __launch_bounds__(256) void sum_kernel(
    const float* __restrict__ in, const float* __restrict__ w,
    float* __restrict__ S, unsigned short* __restrict__ Wf)
{
    const int blk = blockIdx.x;
    const int tid = threadIdx.x;
    if (blk < B_ * H_) {
        __shared__ f32x4 red[8][28];
        const int b = blk / H_, h = blk % H_;
        if (tid < 224) {
            const int cg = tid / 28, ws = tid % 28;
            const float* p = in + ((size_t)(b * CIN + cg * 16) * H_ + h) * W_ + 4 * ws;
            f32x4 acc = (f32x4){0.f, 0.f, 0.f, 0.f};
            #pragma unroll
            for (int k = 0; k < 16; ++k)
                acc += *reinterpret_cast<const f32x4*>(p + (size_t)k * HW);
            red[cg][ws] = acc;
        }
        __syncthreads();
        if (tid < 28) {
            f32x4 s = red[0][tid];
            #pragma unroll
            for (int g = 1; g < 8; ++g) s += red[g][tid];
            *reinterpret_cast<f32x4*>(S + (size_t)(b * H_ + h) * W_ + 4 * tid) = s;
        }
    } else {
        int cid = (blk - B_ * H_) * 256 + tid;     // ((t*4+c0)*16+g)*64+L
        if (cid < 9 * 4 * 16 * 64) {
            int L   = cid & 63;
            int g   = (cid >> 6) & 15;
            int c0  = (cid >> 10) & 3;
            int t   = cid >> 12;
            int o   = g * 16 + (L & 15);
            int cb  = c0 * 32 + (L >> 4) * 8;
            u16x8 v;
            #pragma unroll
            for (int e = 0; e < 8; ++e)
                v[e] = f2bf(w[(size_t)(o * CIN + cb + e) * 9 + t]);
            *reinterpret_cast<u16x8*>(Wf + (size_t)cid * 8) = v;
        }
    }
}

// ---------------------------------------------------------------------------
// K2: T[b,y,x] = 0.1 * (sum 5x5 window - even-even 3x3 subgrid) of S.
//     Block=(b,y): stage the 5 needed S rows into LDS (f32x4, coalesced),
//     then 25 LDS reads per output x.
// ---------------------------------------------------------------------------
__global__ __launch_bounds__(128) void t_kernel(
    const float* __restrict__ S, float* __restrict__ T)
{
    __shared__ float Sr[5][112];
    const int blk = blockIdx.x;
    const int tid = threadIdx.x;
    const int b = blk / HO, y = blk % HO;
    for (int task = tid; task < 5 * 28; task += 128) {
        int row = task / 28, w4 = task % 28;
        *reinterpret_cast<f32x4*>(&Sr[row][4 * w4]) =
            *reinterpret_cast<const f32x4*>(S + (size_t)(b * H_ + 2 * y + row) * W_ + 4 * w4);
    }
    __syncthreads();
    if (tid < WO) {
        int x = tid;
        float s25 = 0.f, s9 = 0.f;
        #pragma unroll
        for (int i = 0; i < 5; ++i) {
            #pragma unroll
            for (int j = 0; j < 5; ++j) {
                float v = Sr[i][2 * x + j];
                s25 += v;
                if (!(i & 1) && !(j & 1)) s9 += v;
            }
        }
        T[(size_t)b * M_PER_B + y * WO + x] = 0.1f * (s25 - s9);
    }
}

// ---------------------------------------------------------------------------
// K3: conv — BYTE-IDENTICAL to the verified round-3 kernel (72 us, passed).
// Block = (b, y): stages 3 even input rows (fp32, L3-resident) as bf16
// channel-last into XOR-swizzled LDS, then 36 K-steps with 2-deep B
// prefetch. 4 waves, each 64m x 64n (acc[4][4]).
// ---------------------------------------------------------------------------
__global__ __launch_bounds__(256, 3) void conv_kernel(
    const float* __restrict__ in, const unsigned short* __restrict__ Wf,
    const float* __restrict__ T, const float* __restrict__ bias1,
    float* __restrict__ out)
{
    __shared__ unsigned short patch[168 * 128];      // 43,008 B

    const int tid = threadIdx.x;
    int bid = blockIdx.x;
    int wg  = (bid & 7) * 108 + (bid >> 3);          // XCD-contiguous (864%8==0)
    const int b = wg / HO;
    const int y = wg % HO;

    // stage: rows h = 2y, 2y+2, 2y+4; all 128 c, all 112 w; keep even w as bf16
    const float* inb = in + (size_t)b * CIN * HW;
    #pragma unroll
    for (int it = 0; it < 42; ++it) {
        int ch = tid + it * 256;          // ((c*3+r)*28+ws)
        int ws = ch % 28;
        int cr = ch / 28;
        int r  = cr % 3;
        int c  = cr / 3;
        f32x4 v = *reinterpret_cast<const f32x4*>(
            inb + ((size_t)c * H_ + (2 * y + 2 * r)) * W_ + 4 * ws);
        int p0 = r * 56 + 2 * ws;
        patch[p0 * 128 + (c ^ ((p0 & 7) << 3))] = f2bf(v[0]);
        int p1 = p0 + 1;
        patch[p1 * 128 + (c ^ ((p1 & 7) << 3))] = f2bf(v[2]);
    }
    __syncthreads();

    const int lane = tid & 63;
    const int wn   = tid >> 6;        // 0..3: n-group of 64 cols
    const int lm   = lane & 15;
    const int kq   = lane >> 4;
    const int koff = kq * 8;

    int xm[4];
    #pragma unroll
    for (int mi = 0; mi < 4; ++mi) {
        int x = mi * 16 + lm;
        xm[mi] = (x > 53) ? 53 : x;
    }

    f32x4 acc[4][4];
    #pragma unroll
    for (int mi = 0; mi < 4; ++mi)
        #pragma unroll
        for (int ni = 0; ni < 4; ++ni)
            acc[mi][ni] = (f32x4){0.f, 0.f, 0.f, 0.f};

    const unsigned short* wfl = Wf + (size_t)(wn * 4) * 512 + lane * 8;

    bf16x8 bb[2][4];
    #pragma unroll
    for (int ni = 0; ni < 4; ++ni)
        bb[0][ni] = __builtin_bit_cast(bf16x8,
            *reinterpret_cast<const u16x8*>(wfl + ni * 512));

    #pragma unroll
    for (int s = 0; s < 36; ++s) {
        const int cur = s & 1;
        if (s + 1 < 36) {
            const unsigned short* wnx = wfl + (size_t)(s + 1) * 16 * 512;
            #pragma unroll
            for (int ni = 0; ni < 4; ++ni)
                bb[cur ^ 1][ni] = __builtin_bit_cast(bf16x8,
                    *reinterpret_cast<const u16x8*>(wnx + ni * 512));
        }
        const int t  = s >> 2, c0 = s & 3;
        const int ki = t / 3, kj = t % 3;
        bf16x8 a[4];
        #pragma unroll
        for (int mi = 0; mi < 4; ++mi) {
            int pos = ki * 56 + kj + xm[mi];
            int sa  = pos * 128 + ((c0 * 32 + koff) ^ ((pos & 7) << 3));
            a[mi] = __builtin_bit_cast(bf16x8,
                *reinterpret_cast<const u16x8*>(&patch[sa]));
        }
        #pragma unroll
        for (int mi = 0; mi < 4; ++mi)
            #pragma unroll
            for (int ni = 0; ni < 4; ++ni)
                acc[mi][ni] = __builtin_amdgcn_mfma_f32_16x16x32_bf16(
                    a[mi], bb[cur][ni], acc[mi][ni], 0, 0, 0);
    }

    // epilogue: out[b][o][y*54+x] = acc + bias1[o]*T[b][y*54+x]
    const float* Trow = T + (size_t)b * M_PER_B + y * WO;
    float* obase = out + (size_t)b * COUT * M_PER_B + y * WO;
    #pragma unroll
    for (int mi = 0; mi < 4; ++mi) {
        int mb = mi * 16 + kq * 4;
        if (mb >= WO) continue;
        bool full = (mb + 4 <= WO);
        float tv0 = Trow[mb], tv1 = Trow[mb + 1];
        float tv2 = 0.f, tv3 = 0.f;
        if (full) { tv2 = Trow[mb + 2]; tv3 = Trow[mb + 3]; }
        #pragma unroll
        for (int ni = 0; ni < 4; ++ni) {
            int o = wn * 64 + ni * 16 + lm;
            float bo = bias1[o];
            float* op = obase + (size_t)o * M_PER_B + mb;
            float2 r01 = make_float2(acc[mi][ni][0] + bo * tv0,
                                     acc[mi][ni][1] + bo * tv1);
            *reinterpret_cast<float2*>(op) = r01;
            if (full) {
                float2 r23 = make_float2(acc[mi][ni][2] + bo * tv2,
                                         acc[mi][ni][3] + bo * tv3);
                *reinterpret_cast<float2*>(op + 2) = r23;
            }
        }
    }
}

// ---------------------------------------------------------------------------
extern "C" void kernel_launch(void* const* d_in, const int* in_sizes, int n_in,
                              void* d_out, int out_size, void* d_ws, size_t ws_size,
                              hipStream_t stream)
{
    const float* in = (const float*)d_in[0];
    const float* w  = (const float*)d_in[1];
    const float* b1 = (const float*)d_in[2];
    float* out = (float*)d_out;

    char* ws = (char*)d_ws;
    float* S = (float*)ws;                                     // 16*112*112*4 = 802,816
    size_t off = 802816;
    float* T = (float*)(ws + off);  off += 186624;             // 16*2916*4
    unsigned short* Wf = (unsigned short*)(ws + off);          // 589,824

    sum_kernel<<<dim3(B_ * H_ + 144), 256, 0, stream>>>(in, w, S, Wf);
    t_kernel<<<dim3(B_ * HO), 128, 0, stream>>>(S, T);
    conv_kernel<<<dim3(HO * B_), 256, 0, stream>>>(in, Wf, T, b1, out);
}